// Round 1
// baseline (572.291 us; speedup 1.0000x reference)
//
#include <hip/hip_runtime.h>
#include <math.h>

// Dale CB-cell recurrent update.
// H=48, IN=8, B=1048576, DT=0.1, fp32 throughout.
//
// Structure: one lane per batch element (outer-product GEMM form).
// Weights are wave-uniform -> scalar loads broadcast into v_fmac_f32.
// r (sigmoid of v) lives in LDS [k][tid] to avoid runtime-indexed
// register arrays (scratch trap), read back 4/group with 1-ahead prefetch.
// Two matvec passes (z-path then v-path) to cap live VGPRs at ~130.

#define DTC 0.1f

// ws layout (floats):
//   [0    , 2304) KspT[k*48+h]  = softplus(K)[h][k]
//   [2304 , 4608) WT  [k*48+h]  = Dale-constrained W[h][k]
//   [4608 , 4992) PzT [j*48+h]  = P_z[h][j]
//   [4992 , 5376) PmT [j*48+h]  = (P * row_mask)[h][j]
//   [5376 , 5424) b_z[48]
//   [5424 , 5472) b_v[48]

__global__ void prep_kernel(const float* __restrict__ P,
                            const float* __restrict__ b_v,
                            const float* __restrict__ K,
                            const float* __restrict__ C,
                            const float* __restrict__ P_z,
                            const float* __restrict__ b_z,
                            const float* __restrict__ e_e,
                            const float* __restrict__ e_i,
                            float* __restrict__ ws)
{
    const float ee = e_e[0];
    const float ei = e_i[0];
    for (int idx = threadIdx.x; idx < 2304; idx += blockDim.x) {
        const int h = idx / 48;
        const int k = idx % 48;
        const float ksp = log1pf(expf(K[idx]));   // softplus, x small -> stable
        const float csp = log1pf(expf(C[idx]));
        const float S   = ksp + csp;
        // cols < 24: excitatory relu(e_e*S) >= 0 ; cols >= 24: inhibitory <= 0
        const float w = (k < 24) ? fmaxf(0.0f, ee * S) : fminf(0.0f, ei * S);
        ws[k * 48 + h]        = ksp;
        ws[2304 + k * 48 + h] = w;
    }
    for (int idx = threadIdx.x; idx < 384; idx += blockDim.x) {
        const int h = idx / 8;
        const int j = idx % 8;
        // rows [12,24) and [36,48) masked off
        const float mask = ((h / 12) & 1) ? 0.0f : 1.0f;
        ws[4608 + j * 48 + h] = P_z[idx];
        ws[4992 + j * 48 + h] = P[idx] * mask;
    }
    for (int idx = threadIdx.x; idx < 48; idx += blockDim.x) {
        ws[5376 + idx] = b_z[idx];
        ws[5424 + idx] = b_v[idx];
    }
}

__device__ __forceinline__ float fast_sigmoid(float x) {
    const float e = __expf(-x);
    return __builtin_amdgcn_rcpf(1.0f + e);
}

// One matvec pass: acc[h] = bias[h] + sum_j PT[j][h]*x[j] + sum_k WT[k][h]*r[k]
// rc = &r_lds[tid], stride 256 floats per k. Inlined so addrspace(3) is known.
__device__ __forceinline__ void matvec_pass(const float* __restrict__ WT,
                                            const float* __restrict__ PT,
                                            const float* __restrict__ bias,
                                            const float* rc,
                                            const float* xv,
                                            float* acc)
{
    #pragma unroll
    for (int h = 0; h < 48; ++h) acc[h] = bias[h];
    #pragma unroll
    for (int j = 0; j < 8; ++j) {
        const float xj = xv[j];
        #pragma unroll
        for (int h = 0; h < 48; ++h)
            acc[h] = fmaf(PT[j * 48 + h], xj, acc[h]);
    }
    float cur[4], nxt[4];
    #pragma unroll
    for (int j = 0; j < 4; ++j) cur[j] = rc[j * 256];
    #pragma unroll 1
    for (int kg = 0; kg < 12; ++kg) {
        const int kn = (kg + 1 < 12) ? (kg + 1) : 11;   // harmless dup prefetch on last iter
        #pragma unroll
        for (int j = 0; j < 4; ++j) nxt[j] = rc[(kn * 4 + j) * 256];
        const float* wp = WT + kg * 192;
        #pragma unroll
        for (int j = 0; j < 4; ++j) {
            const float rk = cur[j];
            #pragma unroll
            for (int h = 0; h < 48; ++h)
                acc[h] = fmaf(wp[j * 48 + h], rk, acc[h]);
        }
        #pragma unroll
        for (int j = 0; j < 4; ++j) cur[j] = nxt[j];
    }
}

__global__ void __launch_bounds__(256) dale_main(const float* __restrict__ hidden,
                                                 const float* __restrict__ x,
                                                 const float* __restrict__ ws,
                                                 float* __restrict__ out,
                                                 int B)
{
    __shared__ float r_lds[48 * 256];   // [k][tid], bank = tid%32 -> conflict-free
    const int tid = threadIdx.x;
    const long b = (long)blockIdx.x * 256 + tid;
    if (b >= B) return;

    const float* __restrict__ KspT = ws;
    const float* __restrict__ WT   = ws + 2304;
    const float* __restrict__ PzT  = ws + 4608;
    const float* __restrict__ PmT  = ws + 4992;
    const float* __restrict__ bz   = ws + 5376;
    const float* __restrict__ bv   = ws + 5424;

    // v: this element's 48-float hidden row (contiguous, 16B-aligned)
    float v[48];
    {
        const float4* hp = reinterpret_cast<const float4*>(hidden + b * 48);
        #pragma unroll
        for (int i = 0; i < 12; ++i) {
            const float4 t = hp[i];
            v[4 * i + 0] = t.x; v[4 * i + 1] = t.y;
            v[4 * i + 2] = t.z; v[4 * i + 3] = t.w;
        }
    }
    // r = sigmoid(v) -> LDS (own column only; no cross-thread use, no barrier)
    #pragma unroll
    for (int k = 0; k < 48; ++k)
        r_lds[k * 256 + tid] = fast_sigmoid(v[k]);

    float xv[8];
    #pragma unroll
    for (int j = 0; j < 8; ++j) xv[j] = x[(long)j * B + b];

    const float* rc = &r_lds[tid];
    float acc[48];

    // ---- pass 1: z = DT * sigmoid(Ksp@r + Pz@x + bz); fold v *= (1-z) ----
    matvec_pass(KspT, PzT, bz, rc, xv, acc);
    #pragma unroll
    for (int h = 0; h < 48; ++h) {
        const float z = DTC * fast_sigmoid(acc[h]);
        v[h] = (1.0f - z) * v[h];
    }

    // ---- pass 2: v_new = v*(1-z) + DT*(W@r + Pm@x + bv) ----
    matvec_pass(WT, PmT, bv, rc, xv, acc);
    #pragma unroll
    for (int h = 0; h < 48; ++h)
        v[h] = fmaf(DTC, acc[h], v[h]);

    float4* op = reinterpret_cast<float4*>(out + b * 48);
    #pragma unroll
    for (int i = 0; i < 12; ++i) {
        float4 t;
        t.x = v[4 * i + 0]; t.y = v[4 * i + 1];
        t.z = v[4 * i + 2]; t.w = v[4 * i + 3];
        op[i] = t;
    }
}

extern "C" void kernel_launch(void* const* d_in, const int* in_sizes, int n_in,
                              void* d_out, int out_size, void* d_ws, size_t ws_size,
                              hipStream_t stream) {
    const float* hidden = (const float*)d_in[0];
    const float* x      = (const float*)d_in[1];
    const float* P      = (const float*)d_in[2];
    const float* b_v    = (const float*)d_in[3];
    const float* K      = (const float*)d_in[4];
    const float* C      = (const float*)d_in[5];
    const float* P_z    = (const float*)d_in[6];
    const float* b_z    = (const float*)d_in[7];
    const float* e_e    = (const float*)d_in[8];
    const float* e_i    = (const float*)d_in[9];
    float* out = (float*)d_out;
    float* ws  = (float*)d_ws;
    const int B = in_sizes[0] / 48;

    prep_kernel<<<dim3(1), dim3(256), 0, stream>>>(P, b_v, K, C, P_z, b_z, e_e, e_i, ws);
    dale_main<<<dim3((B + 255) / 256), dim3(256), 0, stream>>>(hidden, x, ws, out, B);
}